// Round 12
// baseline (329.496 us; speedup 1.0000x reference)
//
#include <hip/hip_runtime.h>

// TrueEpisodicMemory round 12: round-11 base (HW-passed, 296us) + ONE change: PV MFMA
// operand swap. o = mfma(V_frag, P_frag) makes the D fragment hold 4 CONSECUTIVE out
// columns per lane (D col=lane&15 -> out row, D row=4*lk+r -> out col), so each lane
// issues 2 x dwordx4 NT stores per step instead of 8 scalar dword stores (4x fewer).
// Everything else (staging, swizzles, softmax, QK ledger) verbatim from round 11.
// out[b,:] = softmax_m(q[b]·mk[m] + 0.5*cx[b]·mc[m] + exp(0.1*ts[m])) · mv
// B=131072, M=100 (pad 112/128), D=1024, C=16.

typedef __attribute__((ext_vector_type(8))) _Float16 f16x8;
typedef __attribute__((ext_vector_type(4))) float f32x4;

constexpr int DQ = 1024, CD = 16, MM = 100, KD = 1056, NT = 7;
constexpr size_t KE = (size_t)112 * KD;

// LDS (bytes): QK phase: Q[3][128][8 slot][16] @0 (16 KB ea), K[3][112][4 slot][16] @49152.
// PV phase overlay: P[8 wave][16][128]f16 @0 (32 KB), V[3][32][16 slot][16] @32768 (8 KB ea).
constexpr int QBUF = 16384, KOFF = 49152, KBUF = 7168;
constexpr int VOFF = 32768, VBUF = 8192;
constexpr int LDSZ = 70656;

#define WAITV(n) asm volatile("s_waitcnt vmcnt(" #n ")" ::: "memory")

__device__ __forceinline__ void gl16(const void* g, void* l) {
    __builtin_amdgcn_global_load_lds(
        (const __attribute__((address_space(1))) unsigned int*)g,
        (__attribute__((address_space(3))) unsigned int*)l, 16, 0, 0);
}

// ---------------- prologue: fp16 K [112][1056], ctx folded at cols 1024..1039 ----------------
__global__ void build_k(const float* __restrict__ mk, const float* __restrict__ mc,
                        _Float16* __restrict__ KH)
{
    int d = blockIdx.x * 64 + threadIdx.x;
    int m = blockIdx.y;
    if (d >= KD) return;
    float x = 0.f;
    if (m < MM) {
        if (d < DQ)            x = mk[(size_t)m * DQ + d];
        else if (d < DQ + CD)  x = 0.5f * mc[(size_t)m * CD + (d - DQ)];
    }
    KH[(size_t)m * KD + d] = (_Float16)x;
}

// ---------------- prologue: fp16 V^T [1024][128] (cols 100..127 zero) ----------------
__global__ void build_vt(const float* __restrict__ mv, _Float16* __restrict__ VT)
{
    int idx = blockIdx.x * 256 + threadIdx.x;   // 0..131071
    int d = idx >> 7, m = idx & 127;
    VT[idx] = (m < MM) ? (_Float16)mv[(size_t)m * DQ + d] : (_Float16)0.f;
}

// ---------------- main fused kernel: 512 threads, 128 rows/block ----------------
__global__ __launch_bounds__(512, 4)
void epmem_pipe(const float* __restrict__ q, const float* __restrict__ cx,
                const float* __restrict__ ts,
                const _Float16* __restrict__ KH, const _Float16* __restrict__ VT,
                float* __restrict__ out)
{
    __shared__ __align__(16) char lds[LDSZ];

    const int t = threadIdx.x, w = t >> 6, lane = t & 63;
    const int lr = lane & 15, lk = lane >> 4;
    const int row0 = blockIdx.x * 128;

    // time-decay bias first: these vmem loads are oldest -> drained by the first WAITV
    float dec[NT];
    #pragma unroll
    for (int nt = 0; nt < NT; ++nt) {
        int m = nt * 16 + lr;
        dec[nt] = (m < MM) ? __expf(0.1f * ts[m]) : 0.f;
    }

    // ---- staging (linear LDS dest = wave-uniform base + lane*16; swizzle on global src) ----
    auto stageQ = [&](int buf, int ks) {            // 1024 segs, 2/thread
        char* dst = lds + buf * QBUF;
        #pragma unroll
        for (int i = 0; i < 2; ++i) {
            int s = i * 512 + w * 64 + lane;        // seg: row s>>3, phys slot s&7
            int row = s >> 3;
            int logical = (s & 7) ^ (row & 7);
            gl16(q + (size_t)(row0 + row) * DQ + ks * 32 + logical * 4,
                 dst + (i * 512 + w * 64) * 16);
        }
    };
    auto stageQctx = [&](int buf) {                 // [128][4 slot] packed, 512 segs, 1/thread
        char* dst = lds + buf * QBUF;
        gl16(cx + (size_t)(row0 + (t >> 2)) * CD + (t & 3) * 4, dst + (w * 64) * 16);
    };
    auto stageK = [&](int buf, int ks) {            // 448 segs, 1/thread for w<7
        if (w < 7) {
            char* dst = lds + KOFF + buf * KBUF;
            int s = w * 64 + lane;                  // seg: m s>>2, phys slot s&3
            int m = s >> 2;
            int logical = (s & 3) ^ ((m >> 1) & 3);
            gl16(KH + (size_t)m * KD + ks * 32 + logical * 8, dst + (w * 64) * 16);
        }
    };
    auto stageV = [&](int buf, int c) {             // 512 segs, 1/thread
        char* dst = lds + VOFF + buf * VBUF;
        int d = t >> 4;                             // 0..31
        int logical = (t & 15) ^ (d & 15);
        gl16(VT + (size_t)(c * 32 + d) * 128 + logical * 8, dst + (w * 64) * 16);
    };

    f32x4 acc[NT];
    #pragma unroll
    for (int nt = 0; nt < NT; ++nt) acc[nt] = (f32x4){0.f, 0.f, 0.f, 0.f};

    // ---------- QK^T: 33 chunk-steps (chunk 32 = ctx), depth-3, counted vmcnt ----------
    stageQ(0, 0); stageK(0, 0);
    stageQ(1, 1); stageK(1, 1);
    if (w < 7) { WAITV(3); } else { WAITV(2); }     // chunk 0 resident; chunk 1 in flight
    __builtin_amdgcn_s_barrier();

    int bc = 0;
    for (int ks = 0; ks <= 32; ++ks) {
        int bs = bc + 2; if (bs >= 3) bs -= 3;
        if (ks + 2 < 32)       { stageQ(bs, ks + 2); stageK(bs, ks + 2); }
        else if (ks + 2 == 32) { stageQctx(bs);      stageK(bs, 32); }

        const char* qb = lds + bc * QBUF;
        f16x8 ah, al;
        if (ks < 32) {
            const char* base = qb + (w * 16 + lr) * 128;
            const int g = lr & 7;
            f32x4 x = *(const f32x4*)(base + (((2 * lk)     ^ g) << 4));
            f32x4 y = *(const f32x4*)(base + (((2 * lk + 1) ^ g) << 4));
            #pragma unroll
            for (int e = 0; e < 4; ++e) {
                _Float16 h = (_Float16)x[e]; ah[e] = h;     al[e] = (_Float16)(x[e] - (float)h);
                h = (_Float16)y[e];          ah[4 + e] = h; al[4 + e] = (_Float16)(y[e] - (float)h);
            }
        } else {
            if (lk < 2) {
                const char* base = qb + (w * 16 + lr) * 64;
                f32x4 x = *(const f32x4*)(base + (2 * lk) * 16);
                f32x4 y = *(const f32x4*)(base + (2 * lk + 1) * 16);
                #pragma unroll
                for (int e = 0; e < 4; ++e) {
                    _Float16 h = (_Float16)x[e]; ah[e] = h;     al[e] = (_Float16)(x[e] - (float)h);
                    h = (_Float16)y[e];          ah[4 + e] = h; al[4 + e] = (_Float16)(y[e] - (float)h);
                }
            } else {
                #pragma unroll
                for (int e = 0; e < 8; ++e) { ah[e] = (_Float16)0.f; al[e] = (_Float16)0.f; }
            }
        }
        #pragma unroll
        for (int nt = 0; nt < NT; ++nt) {
            int m = nt * 16 + lr;
            f16x8 bh = *(const f16x8*)(lds + KOFF + bc * KBUF
                         + ((m << 2) + (lk ^ ((lr >> 1) & 3))) * 16);
            acc[nt] = __builtin_amdgcn_mfma_f32_16x16x32_f16(ah, bh, acc[nt], 0, 0, 0);
            acc[nt] = __builtin_amdgcn_mfma_f32_16x16x32_f16(al, bh, acc[nt], 0, 0, 0);
        }
        // counted waits: chunk ks+1 resident before next step; never drain mid-loop
        if (ks <= 29)      { if (w < 7) { WAITV(3); } else { WAITV(2); } }
        else if (ks == 30) { if (w < 7) { WAITV(2); } else { WAITV(1); } }
        else if (ks == 31) { WAITV(0); }
        if (ks < 32) __builtin_amdgcn_s_barrier();
        if (++bc == 3) bc = 0;
    }

    __builtin_amdgcn_s_barrier();               // all QK LDS reads done; V/P may overlay
    stageV(0, 0); stageV(1, 1);                 // V latency hides under softmax

    // ---------- softmax, fully in-register (wave owns rows w*16..w*16+15) ----------
    char* Pb = lds + w * 4096;                  // wave-private P [16][128]f16, slot-swizzled
    {
        float rm[4] = {-3e38f, -3e38f, -3e38f, -3e38f};
        #pragma unroll
        for (int nt = 0; nt < NT; ++nt) {
            int m = nt * 16 + lr;
            #pragma unroll
            for (int r = 0; r < 4; ++r) {
                float s = (m < MM) ? (acc[nt][r] + dec[nt]) : -3e38f;
                acc[nt][r] = s;
                rm[r] = fmaxf(rm[r], s);
            }
        }
        #pragma unroll
        for (int r = 0; r < 4; ++r)
            #pragma unroll
            for (int off = 1; off < 16; off <<= 1)
                rm[r] = fmaxf(rm[r], __shfl_xor(rm[r], off));
        float rs[4] = {0.f, 0.f, 0.f, 0.f};
        #pragma unroll
        for (int nt = 0; nt < NT; ++nt)
            #pragma unroll
            for (int r = 0; r < 4; ++r) {
                float e = __expf(acc[nt][r] - rm[r]);
                acc[nt][r] = e;
                rs[r] += e;
            }
        #pragma unroll
        for (int r = 0; r < 4; ++r)
            #pragma unroll
            for (int off = 1; off < 16; off <<= 1)
                rs[r] += __shfl_xor(rs[r], off);
        #pragma unroll
        for (int r = 0; r < 4; ++r) {
            float inv = 1.f / rs[r];
            int row = 4 * lk + r;
            #pragma unroll
            for (int nt = 0; nt < NT; ++nt)
                *(_Float16*)(Pb + row * 256 + (((nt * 2 + (lr >> 3)) ^ row) & 15) * 16
                             + (lr & 7) * 2) = (_Float16)(acc[nt][r] * inv);
        }
    }
    if (lane < 32) {                            // zero-pad P cols 112..127 (slots 14,15)
        int row = lane >> 1, sl = 14 + (lane & 1);
        uint4 z = {0u, 0u, 0u, 0u};
        *(uint4*)(Pb + row * 256 + ((sl ^ row) & 15) * 16) = z;
    }
    WAITV(1);                                   // V chunk 0 resident; chunk 1 in flight
    __builtin_amdgcn_s_barrier();

    // ---------- PV: 32 d-chunk steps, depth-3; SWAPPED MFMA operands -> wide stores ----------
    f16x8 pa[4];
    #pragma unroll
    for (int k4 = 0; k4 < 4; ++k4)
        pa[k4] = *(const f16x8*)(Pb + lr * 256 + (((k4 * 4 + lk) ^ lr) & 15) * 16);

    int vc = 0;
    for (int c = 0; c < 32; ++c) {
        int vs = vc + 2; if (vs >= 3) vs -= 3;
        if (c + 2 < 32) stageV(vs, c + 2);
        f32x4 o0 = {0.f, 0.f, 0.f, 0.f}, o1 = {0.f, 0.f, 0.f, 0.f};
        #pragma unroll
        for (int k4 = 0; k4 < 4; ++k4) {
            const char* vb = lds + VOFF + vc * VBUF + (((k4 * 4 + lk) ^ lr) & 15) * 16;
            f16x8 b0 = *(const f16x8*)(vb + lr * 256);          // d = lr
            f16x8 b1 = *(const f16x8*)(vb + (16 + lr) * 256);   // d = 16+lr (same swizzle: d&15=lr)
            // SWAPPED: A := V fragment (rows = out cols), B := P fragment (rows = out rows).
            // D: col(lane&15=lr) -> out row w*16+lr; row(4*lk+r) -> out col c*32(+16)+4*lk+r.
            o0 = __builtin_amdgcn_mfma_f32_16x16x32_f16(b0, pa[k4], o0, 0, 0, 0);
            o1 = __builtin_amdgcn_mfma_f32_16x16x32_f16(b1, pa[k4], o1, 0, 0, 0);
        }
        {
            size_t rw = (size_t)(row0 + w * 16 + lr) * DQ + c * 32 + 4 * lk;
            __builtin_nontemporal_store(o0, (f32x4*)&out[rw]);        // 16 B contiguous
            __builtin_nontemporal_store(o1, (f32x4*)&out[rw + 16]);   // 16 B contiguous
        }
        // Ledger (2 stores + 1 stage per step): need V(c+1) before next step.
        if (c == 0)       { WAITV(3); }         // newer than V(1): V(2) + 2 stores
        else if (c <= 29) { WAITV(5); }         // stores(c-1) 2 + V(c+2) 1 + stores(c) 2
        else if (c == 30) { WAITV(4); }         // no V(32): stores(29) 2 + stores(30) 2
        if (c < 31) __builtin_amdgcn_s_barrier();
        if (++vc == 3) vc = 0;
    }
}

extern "C" void kernel_launch(void* const* d_in, const int* in_sizes, int n_in,
                              void* d_out, int out_size, void* d_ws, size_t ws_size,
                              hipStream_t stream) {
    const float* q  = (const float*)d_in[0];
    const float* cx = (const float*)d_in[1];
    const float* mk = (const float*)d_in[2];
    const float* mv = (const float*)d_in[3];
    const float* mc = (const float*)d_in[4];
    const float* ts = (const float*)d_in[5];
    float* out = (float*)d_out;

    _Float16* wsp = (_Float16*)d_ws;
    _Float16* KH = wsp;                        // [112][1056]
    _Float16* VT = wsp + KE;                   // [1024][128]

    const int B = in_sizes[0] / DQ;            // 131072

    build_k<<<dim3(17, 112), dim3(64), 0, stream>>>(mk, mc, KH);
    build_vt<<<dim3(512), dim3(256), 0, stream>>>(mv, VT);
    epmem_pipe<<<dim3(B / 128), dim3(512), 0, stream>>>(q, cx, ts, KH, VT, out);
}

// Round 13
// 317.748 us; speedup vs baseline: 1.0370x; 1.0370x over previous
//
#include <hip/hip_runtime.h>

// TrueEpisodicMemory round 13: r11 base (HW-passed, 296us; r12's swap reverted) + ONE
// structural change: Q is NOT staged through LDS (no cross-wave sharing existed — each
// wave read only its own 16 rows). A-fragments load straight from global q into
// registers (2x dwordx4 NT per step, depth-2 prefetch, static qA/qB sets). ctx staged
// once to LDS in prologue (r11 packed layout). K/softmax/P/V/PV/out: r11 verbatim.
// out[b,:] = softmax_m(q[b]·mk[m] + 0.5*cx[b]·mc[m] + exp(0.1*ts[m])) · mv
// B=131072, M=100 (pad 112/128), D=1024, C=16.

typedef __attribute__((ext_vector_type(8))) _Float16 f16x8;
typedef __attribute__((ext_vector_type(4))) float f32x4;

constexpr int DQ = 1024, CD = 16, MM = 100, KD = 1056, NT = 7;
constexpr size_t KE = (size_t)112 * KD;

// LDS (bytes): QK phase: ctx[128][4 slot][16] @0 (8 KB, staged once),
//              K[3][112][4 slot][16] @8192 (7168 ea -> 29696).
// PV overlay:  P[8 wave][4096] @0 (32 KB), V[3][32][16 slot][16] @32768 (8 KB ea).
constexpr int KOFF = 8192, KBUF = 7168;
constexpr int VOFF = 32768, VBUF = 8192;
constexpr int LDSZ = 57344;

#define WAITV(n) asm volatile("s_waitcnt vmcnt(" #n ")" ::: "memory")

__device__ __forceinline__ void gl16(const void* g, void* l) {
    __builtin_amdgcn_global_load_lds(
        (const __attribute__((address_space(1))) unsigned int*)g,
        (__attribute__((address_space(3))) unsigned int*)l, 16, 0, 0);
}

// ---------------- prologue: fp16 K [112][1056], ctx folded at cols 1024..1039 ----------------
__global__ void build_k(const float* __restrict__ mk, const float* __restrict__ mc,
                        _Float16* __restrict__ KH)
{
    int d = blockIdx.x * 64 + threadIdx.x;
    int m = blockIdx.y;
    if (d >= KD) return;
    float x = 0.f;
    if (m < MM) {
        if (d < DQ)            x = mk[(size_t)m * DQ + d];
        else if (d < DQ + CD)  x = 0.5f * mc[(size_t)m * CD + (d - DQ)];
    }
    KH[(size_t)m * KD + d] = (_Float16)x;
}

// ---------------- prologue: fp16 V^T [1024][128] (cols 100..127 zero) ----------------
__global__ void build_vt(const float* __restrict__ mv, _Float16* __restrict__ VT)
{
    int idx = blockIdx.x * 256 + threadIdx.x;   // 0..131071
    int d = idx >> 7, m = idx & 127;
    VT[idx] = (m < MM) ? (_Float16)mv[(size_t)m * DQ + d] : (_Float16)0.f;
}

// ---------------- main fused kernel: 512 threads, 128 rows/block ----------------
__global__ __launch_bounds__(512, 4)
void epmem_pipe(const float* __restrict__ q, const float* __restrict__ cx,
                const float* __restrict__ ts,
                const _Float16* __restrict__ KH, const _Float16* __restrict__ VT,
                float* __restrict__ out)
{
    __shared__ __align__(16) char lds[LDSZ];

    const int t = threadIdx.x, w = t >> 6, lane = t & 63;
    const int lr = lane & 15, lk = lane >> 4;
    const int row0 = blockIdx.x * 128;

    // time-decay bias (drained by prologue WAITV(0))
    float dec[NT];
    #pragma unroll
    for (int nt = 0; nt < NT; ++nt) {
        int m = nt * 16 + lr;
        dec[nt] = (m < MM) ? __expf(0.1f * ts[m]) : 0.f;
    }

    auto stageCtx = [&]() {                         // [128][4 slot] packed, 1 gl16/thread
        gl16(cx + (size_t)(row0 + (t >> 2)) * CD + (t & 3) * 4, lds + (w * 64) * 16);
    };
    auto stageK = [&](int buf, int ks) {            // r11 verbatim; 1 gl16/thread for w<7
        if (w < 7) {
            char* dst = lds + KOFF + buf * KBUF;
            int s = w * 64 + lane;                  // seg: m s>>2, phys slot s&3
            int m = s >> 2;
            int logical = (s & 3) ^ ((m >> 1) & 3);
            gl16(KH + (size_t)m * KD + ks * 32 + logical * 8, dst + (w * 64) * 16);
        }
    };
    auto stageV = [&](int buf, int c) {             // r11 verbatim
        char* dst = lds + VOFF + buf * VBUF;
        int d = t >> 4;
        int logical = (t & 15) ^ (d & 15);
        gl16(VT + (size_t)(c * 32 + d) * 128 + logical * 8, dst + (w * 64) * 16);
    };

    f32x4 acc[NT];
    #pragma unroll
    for (int nt = 0; nt < NT; ++nt) acc[nt] = (f32x4){0.f, 0.f, 0.f, 0.f};

    // per-lane q base: row = row0 + w*16 + lr, k-offset 8*lk
    const float* qp = q + (size_t)(row0 + w * 16 + lr) * DQ + 8 * lk;

    // split f32x4 pair -> fp16 hi/lo fragments + 14 MFMAs vs K[ks%3]
    auto qkStep = [&](f32x4 x, f32x4 y, int ks) {
        f16x8 ah, al;
        #pragma unroll
        for (int e = 0; e < 4; ++e) {
            _Float16 h = (_Float16)x[e]; ah[e] = h;     al[e] = (_Float16)(x[e] - (float)h);
            h = (_Float16)y[e];          ah[4 + e] = h; al[4 + e] = (_Float16)(y[e] - (float)h);
        }
        const char* kb = lds + KOFF + (ks % 3) * KBUF;
        #pragma unroll
        for (int nt = 0; nt < NT; ++nt) {
            int m = nt * 16 + lr;
            f16x8 bh = *(const f16x8*)(kb + ((m << 2) + (lk ^ ((lr >> 1) & 3))) * 16);
            acc[nt] = __builtin_amdgcn_mfma_f32_16x16x32_f16(ah, bh, acc[nt], 0, 0, 0);
            acc[nt] = __builtin_amdgcn_mfma_f32_16x16x32_f16(al, bh, acc[nt], 0, 0, 0);
        }
    };

    // ---------- QK^T: 32 register-A steps + 1 ctx step; K via LDS depth-3 ----------
    stageCtx();
    stageK(0, 0); stageK(1, 1);
    f32x4 qA0 = __builtin_nontemporal_load((const f32x4*)(qp + 0));
    f32x4 qA1 = __builtin_nontemporal_load((const f32x4*)(qp + 4));
    f32x4 qB0 = __builtin_nontemporal_load((const f32x4*)(qp + 32));
    f32x4 qB1 = __builtin_nontemporal_load((const f32x4*)(qp + 36));
    WAITV(0);                                   // one-time full drain (order-robust)
    __builtin_amdgcn_s_barrier();

    for (int ks = 0; ks < 32; ks += 2) {
        // ---- even step ks: consumes qA ----
        stageK((ks + 2) % 3, ks + 2);           // ks+2 <= 32 always here
        f32x4 nx0, nx1;
        if (ks <= 28) {
            nx0 = __builtin_nontemporal_load((const f32x4*)(qp + (ks + 2) * 32));
            nx1 = __builtin_nontemporal_load((const f32x4*)(qp + (ks + 2) * 32 + 4));
        }
        qkStep(qA0, qA1, ks);
        if (ks <= 28) { qA0 = nx0; qA1 = nx1; }
        // ledger: need K(ks+1)+q(ks+1); newer = this step's issues
        if (ks <= 28) { if (w < 7) { WAITV(3); } else { WAITV(2); } }
        else          { if (w < 7) { WAITV(1); } else { WAITV(0); } }   // ks == 30
        __builtin_amdgcn_s_barrier();

        // ---- odd step ks+1: consumes qB ----
        if (ks <= 28) stageK((ks + 3) % 3, ks + 3);
        f32x4 ny0, ny1;
        if (ks <= 28) {
            ny0 = __builtin_nontemporal_load((const f32x4*)(qp + (ks + 3) * 32));
            ny1 = __builtin_nontemporal_load((const f32x4*)(qp + (ks + 3) * 32 + 4));
        }
        qkStep(qB0, qB1, ks + 1);
        if (ks <= 28) { qB0 = ny0; qB1 = ny1; }
        if (ks <= 28) { if (w < 7) { WAITV(3); } else { WAITV(2); } }
        else          { WAITV(0); }             // ks+1 == 31: drain K(32)
        __builtin_amdgcn_s_barrier();
    }

    {   // ---- ctx step (ks = 32): A from ctx LDS (staged in prologue), K buf 32%3 = 2 ----
        f16x8 ah, al;
        if (lk < 2) {
            const char* base = lds + (w * 16 + lr) * 64;
            f32x4 x = *(const f32x4*)(base + (2 * lk) * 16);
            f32x4 y = *(const f32x4*)(base + (2 * lk + 1) * 16);
            #pragma unroll
            for (int e = 0; e < 4; ++e) {
                _Float16 h = (_Float16)x[e]; ah[e] = h;     al[e] = (_Float16)(x[e] - (float)h);
                h = (_Float16)y[e];          ah[4 + e] = h; al[4 + e] = (_Float16)(y[e] - (float)h);
            }
        } else {
            #pragma unroll
            for (int e = 0; e < 8; ++e) { ah[e] = (_Float16)0.f; al[e] = (_Float16)0.f; }
        }
        const char* kb = lds + KOFF + 2 * KBUF;
        #pragma unroll
        for (int nt = 0; nt < NT; ++nt) {
            int m = nt * 16 + lr;
            f16x8 bh = *(const f16x8*)(kb + ((m << 2) + (lk ^ ((lr >> 1) & 3))) * 16);
            acc[nt] = __builtin_amdgcn_mfma_f32_16x16x32_f16(ah, bh, acc[nt], 0, 0, 0);
            acc[nt] = __builtin_amdgcn_mfma_f32_16x16x32_f16(al, bh, acc[nt], 0, 0, 0);
        }
    }
    __syncthreads();                            // QK LDS dead; P/V may overlay

    stageV(0, 0); stageV(1, 1);                 // V latency hides under softmax

    // ---------- softmax, fully in-register (r11 verbatim) ----------
    char* Pb = lds + w * 4096;
    {
        float rm[4] = {-3e38f, -3e38f, -3e38f, -3e38f};
        #pragma unroll
        for (int nt = 0; nt < NT; ++nt) {
            int m = nt * 16 + lr;
            #pragma unroll
            for (int r = 0; r < 4; ++r) {
                float s = (m < MM) ? (acc[nt][r] + dec[nt]) : -3e38f;
                acc[nt][r] = s;
                rm[r] = fmaxf(rm[r], s);
            }
        }
        #pragma unroll
        for (int r = 0; r < 4; ++r)
            #pragma unroll
            for (int off = 1; off < 16; off <<= 1)
                rm[r] = fmaxf(rm[r], __shfl_xor(rm[r], off));
        float rs[4] = {0.f, 0.f, 0.f, 0.f};
        #pragma unroll
        for (int nt = 0; nt < NT; ++nt)
            #pragma unroll
            for (int r = 0; r < 4; ++r) {
                float e = __expf(acc[nt][r] - rm[r]);
                acc[nt][r] = e;
                rs[r] += e;
            }
        #pragma unroll
        for (int r = 0; r < 4; ++r)
            #pragma unroll
            for (int off = 1; off < 16; off <<= 1)
                rs[r] += __shfl_xor(rs[r], off);
        #pragma unroll
        for (int r = 0; r < 4; ++r) {
            float inv = 1.f / rs[r];
            int row = 4 * lk + r;
            #pragma unroll
            for (int nt = 0; nt < NT; ++nt)
                *(_Float16*)(Pb + row * 256 + (((nt * 2 + (lr >> 3)) ^ row) & 15) * 16
                             + (lr & 7) * 2) = (_Float16)(acc[nt][r] * inv);
        }
    }
    if (lane < 32) {                            // zero-pad P cols 112..127 (slots 14,15)
        int row = lane >> 1, sl = 14 + (lane & 1);
        uint4 z = {0u, 0u, 0u, 0u};
        *(uint4*)(Pb + row * 256 + ((sl ^ row) & 15) * 16) = z;
    }
    WAITV(1);                                   // V(0) done (1 newer: V(1))
    __builtin_amdgcn_s_barrier();

    // ---------- PV: 32 d-chunk steps, depth-3, counted vmcnt (r11 verbatim) ----------
    f16x8 pa[4];
    #pragma unroll
    for (int k4 = 0; k4 < 4; ++k4)
        pa[k4] = *(const f16x8*)(Pb + lr * 256 + (((k4 * 4 + lk) ^ lr) & 15) * 16);

    int vc = 0;
    for (int c = 0; c < 32; ++c) {
        int vs = vc + 2; if (vs >= 3) vs -= 3;
        if (c + 2 < 32) stageV(vs, c + 2);
        f32x4 o0 = {0.f, 0.f, 0.f, 0.f}, o1 = {0.f, 0.f, 0.f, 0.f};
        #pragma unroll
        for (int k4 = 0; k4 < 4; ++k4) {
            const char* vb = lds + VOFF + vc * VBUF + (((k4 * 4 + lk) ^ lr) & 15) * 16;
            f16x8 b0 = *(const f16x8*)(vb + lr * 256);          // d = lr
            f16x8 b1 = *(const f16x8*)(vb + (16 + lr) * 256);   // d = 16+lr (d&15 = lr)
            o0 = __builtin_amdgcn_mfma_f32_16x16x32_f16(pa[k4], b0, o0, 0, 0, 0);
            o1 = __builtin_amdgcn_mfma_f32_16x16x32_f16(pa[k4], b1, o1, 0, 0, 0);
        }
        #pragma unroll
        for (int r = 0; r < 4; ++r) {
            size_t rw = (size_t)(row0 + w * 16 + 4 * lk + r) * DQ + c * 32;
            __builtin_nontemporal_store(o0[r], &out[rw + lr]);
            __builtin_nontemporal_store(o1[r], &out[rw + 16 + lr]);
        }
        if (c == 0)       { WAITV(9); }         // V(1) done: newer = V(2)+8 stores
        else if (c <= 29) { WAITV(17); }        // V(c+1) done: newer = 8+1+8
        else if (c == 30) { WAITV(16); }        // no V(32) stage: newer = 8+8
        if (c < 31) __builtin_amdgcn_s_barrier();
        if (++vc == 3) vc = 0;
    }
}

extern "C" void kernel_launch(void* const* d_in, const int* in_sizes, int n_in,
                              void* d_out, int out_size, void* d_ws, size_t ws_size,
                              hipStream_t stream) {
    const float* q  = (const float*)d_in[0];
    const float* cx = (const float*)d_in[1];
    const float* mk = (const float*)d_in[2];
    const float* mv = (const float*)d_in[3];
    const float* mc = (const float*)d_in[4];
    const float* ts = (const float*)d_in[5];
    float* out = (float*)d_out;

    _Float16* wsp = (_Float16*)d_ws;
    _Float16* KH = wsp;                        // [112][1056]
    _Float16* VT = wsp + KE;                   // [1024][128]

    const int B = in_sizes[0] / DQ;            // 131072

    build_k<<<dim3(17, 112), dim3(64), 0, stream>>>(mk, mc, KH);
    build_vt<<<dim3(512), dim3(256), 0, stream>>>(mv, VT);
    epmem_pipe<<<dim3(B / 128), dim3(512), 0, stream>>>(q, cx, ts, KH, VT, out);
}

// Round 14
// 270.291 us; speedup vs baseline: 1.2190x; 1.1756x over previous
//
#include <hip/hip_runtime.h>

// TrueEpisodicMemory round 14: DRAM-page-granularity test INSIDE the proven envelope.
// 64-row blocks (256 thr, 4 waves): q staged in 256-B-per-row chunks (64 k-cols), out
// written in 256-B-per-row steps (64 cols). LDS 65536 <= 70656 (all passing rounds' cap).
// K staging/read, softmax, P layout, V read formula: r11 VERBATIM. Ledgers re-derived
// by explicit queue enumeration (comments show counts).
// out[b,:] = softmax_m(q[b]·mk[m] + 0.5*cx[b]·mc[m] + exp(0.1*ts[m])) · mv
// B=131072, M=100 (pad 112/128), D=1024, C=16.

typedef __attribute__((ext_vector_type(8))) _Float16 f16x8;
typedef __attribute__((ext_vector_type(4))) float f32x4;

constexpr int DQ = 1024, CD = 16, MM = 100, KD = 1056, NT = 7;
constexpr size_t KE = (size_t)112 * KD;

// LDS (bytes):
//  QK: Q[2][64 rows][16 slots x16B] @0 (16 KB ea -> 32 KB); K[3][112][4 slots x16B] @32768
//      (7168 ea -> 21504; end 54272).
//  PV overlay: P[4 waves][4096] @0 (16 KB); V[3][64 rows][16 slots x16B] @16384
//      (16384 ea -> 49152; end 65536).
constexpr int QBUF = 16384, KOFF = 32768, KBUF = 7168;
constexpr int VOFF = 16384, VBUF = 16384;
constexpr int LDSZ = 65536;

#define WAITV(n) asm volatile("s_waitcnt vmcnt(" #n ")" ::: "memory")

__device__ __forceinline__ void gl16(const void* g, void* l) {
    __builtin_amdgcn_global_load_lds(
        (const __attribute__((address_space(1))) unsigned int*)g,
        (__attribute__((address_space(3))) unsigned int*)l, 16, 0, 0);
}

// ---------------- prologue: fp16 K [112][1056], ctx folded at cols 1024..1039 (r11) ----------
__global__ void build_k(const float* __restrict__ mk, const float* __restrict__ mc,
                        _Float16* __restrict__ KH)
{
    int d = blockIdx.x * 64 + threadIdx.x;
    int m = blockIdx.y;
    if (d >= KD) return;
    float x = 0.f;
    if (m < MM) {
        if (d < DQ)            x = mk[(size_t)m * DQ + d];
        else if (d < DQ + CD)  x = 0.5f * mc[(size_t)m * CD + (d - DQ)];
    }
    KH[(size_t)m * KD + d] = (_Float16)x;
}

// ---------------- prologue: fp16 V^T [1024][128] (cols 100..127 zero) (r11) ----------------
__global__ void build_vt(const float* __restrict__ mv, _Float16* __restrict__ VT)
{
    int idx = blockIdx.x * 256 + threadIdx.x;   // 0..131071
    int d = idx >> 7, m = idx & 127;
    VT[idx] = (m < MM) ? (_Float16)mv[(size_t)m * DQ + d] : (_Float16)0.f;
}

// ---------------- main fused kernel: 256 threads, 64 rows/block ----------------
__global__ __launch_bounds__(256, 2)
void epmem_pipe(const float* __restrict__ q, const float* __restrict__ cx,
                const float* __restrict__ ts,
                const _Float16* __restrict__ KH, const _Float16* __restrict__ VT,
                float* __restrict__ out)
{
    __shared__ __align__(16) char lds[LDSZ];

    const int t = threadIdx.x, w = t >> 6, lane = t & 63;
    const int lr = lane & 15, lk = lane >> 4;
    const int row0 = blockIdx.x * 64;

    // time-decay bias first (r11 placement: oldest vmem, hoisted by compiler)
    float dec[NT];
    #pragma unroll
    for (int nt = 0; nt < NT; ++nt) {
        int m = nt * 16 + lr;
        dec[nt] = (m < MM) ? __expf(0.1f * ts[m]) : 0.f;
    }

    // ---- staging: linear LDS dest (wave base + lane*16); swizzle on GLOBAL source ----
    auto stageQ = [&](int buf, int ms) {            // [64 rows][16 slots], 1024 segs, 4/thread
        char* dst = lds + buf * QBUF;               // each instr: 4 rows x 256 B contiguous
        #pragma unroll
        for (int i = 0; i < 4; ++i) {
            int s = i * 256 + t;                    // row s>>4, phys slot s&15
            int row = s >> 4;
            int logical = (s & 15) ^ (row & 15);
            gl16(q + (size_t)(row0 + row) * DQ + ms * 64 + logical * 4,
                 dst + (i * 256 + w * 64) * 16);
        }
    };
    auto stageQctx = [&](int buf) {                 // [64 rows][4 slots] packed, 256 segs
        char* dst = lds + buf * QBUF;
        gl16(cx + (size_t)(row0 + (t >> 2)) * CD + (t & 3) * 4, dst + (w * 64) * 16);
    };
    auto stageK = [&](int buf, int ks) {            // 448 segs, 7 instrs: w0..w2 x2, w3 x1
        char* dst = lds + KOFF + buf * KBUF;
        for (int i = w; i < 7; i += 4) {
            int s = i * 64 + lane;                  // m s>>2, phys slot s&3
            int m = s >> 2;
            int logical = (s & 3) ^ ((m >> 1) & 3);
            gl16(KH + (size_t)m * KD + ks * 32 + logical * 8, dst + (i * 64) * 16);
        }
    };
    auto stageV = [&](int buf, int c) {             // [64 rows][16 slots], 1024 segs, 4/thread
        char* dst = lds + VOFF + buf * VBUF;
        #pragma unroll
        for (int i = 0; i < 4; ++i) {
            int s = i * 256 + t;                    // d s>>4, phys slot s&15
            int d = s >> 4;
            int logical = (s & 15) ^ (d & 15);
            gl16(VT + (size_t)(c * 64 + d) * 128 + logical * 8,
                 dst + (i * 256 + w * 64) * 16);
        }
    };

    f32x4 acc[NT];
    #pragma unroll
    for (int nt = 0; nt < NT; ++nt) acc[nt] = (f32x4){0.f, 0.f, 0.f, 0.f};

    // 14 MFMAs of one 32-col sub-step vs K buffer (read formulas r11-verbatim)
    auto qkStep = [&](const char* qx, const char* qy, const char* kb) {
        f32x4 x = *(const f32x4*)qx, y = *(const f32x4*)qy;
        f16x8 ah, al;
        #pragma unroll
        for (int e = 0; e < 4; ++e) {
            _Float16 h = (_Float16)x[e]; ah[e] = h;     al[e] = (_Float16)(x[e] - (float)h);
            h = (_Float16)y[e];          ah[4 + e] = h; al[4 + e] = (_Float16)(y[e] - (float)h);
        }
        #pragma unroll
        for (int nt = 0; nt < NT; ++nt) {
            int m = nt * 16 + lr;
            f16x8 bh = *(const f16x8*)(kb + ((m << 2) + (lk ^ ((lr >> 1) & 3))) * 16);
            acc[nt] = __builtin_amdgcn_mfma_f32_16x16x32_f16(ah, bh, acc[nt], 0, 0, 0);
            acc[nt] = __builtin_amdgcn_mfma_f32_16x16x32_f16(al, bh, acc[nt], 0, 0, 0);
        }
    };

    // ---------- QK^T: 32 sub-steps of 32 k-cols (Q windows of 64) + ctx sub-step ----------
    // Prologue queue (w<3): [Q0 x4, K0 x2, K1 x2]; need Q0,K0 -> newer than K0 = K1 = 2.
    stageQ(0, 0);
    stageK(0, 0); stageK(1, 1);
    if (w < 3) { WAITV(2); } else { WAITV(1); }
    __builtin_amdgcn_s_barrier();

    for (int ss = 0; ss < 32; ++ss) {
        const int ms = ss >> 1, h = ss & 1;
        if (h == 0) {                               // even: stage next Q window (or ctx)
            if (ms + 1 <= 15)   stageQ((ms + 1) & 1, ms + 1);
            else                stageQctx(0);       // ss == 30: Q(16) -> buf 0
        }
        if (ss <= 30) stageK((ss + 2) % 3, ss + 2);

        const char* base = lds + (ms & 1) * QBUF + (w * 16 + lr) * 256;
        const int u0 = h * 8 + 2 * lk;
        qkStep(base + ((u0 ^ lr) << 4), base + (((u0 + 1) ^ lr) << 4),
               lds + KOFF + (ss % 3) * KBUF);

        // Ledger (queue-enumerated):
        //  even ss (!=30): issues Q4+K(2/1)=6/5; need K(ss+1) (last ops of ss-1) -> 6/5.
        //  even ss==30:    issues ctx1+K(2/1)=3/2 -> WAITV(3)/(2).
        //  odd ss (!=31):  issues K(2/1); need K(ss+1)+Q(ms+1) (staged at ss-1, Q first,
        //                  K last) -> newer than K = odd-ss ops = 2/1.
        //  odd ss==31:     no issues; need K(32)+Qctx (staged at 30) -> WAITV(0).
        if (h == 0) {
            if (ss == 30) { if (w < 3) { WAITV(3); } else { WAITV(2); } }
            else          { if (w < 3) { WAITV(6); } else { WAITV(5); } }
        } else {
            if (ss == 31) { WAITV(0); }
            else          { if (w < 3) { WAITV(2); } else { WAITV(1); } }
        }
        __builtin_amdgcn_s_barrier();
    }
    {   // ctx sub-step (ss=32): Q buf 0 packed [64][4 slots] (r11 read), K buf 32%3 = 2
        f16x8 ah, al;
        if (lk < 2) {
            const char* base = lds + (w * 16 + lr) * 64;
            f32x4 x = *(const f32x4*)(base + (2 * lk) * 16);
            f32x4 y = *(const f32x4*)(base + (2 * lk + 1) * 16);
            #pragma unroll
            for (int e = 0; e < 4; ++e) {
                _Float16 h = (_Float16)x[e]; ah[e] = h;     al[e] = (_Float16)(x[e] - (float)h);
                h = (_Float16)y[e];          ah[4 + e] = h; al[4 + e] = (_Float16)(y[e] - (float)h);
            }
        } else {
            #pragma unroll
            for (int e = 0; e < 8; ++e) { ah[e] = (_Float16)0.f; al[e] = (_Float16)0.f; }
        }
        const char* kb = lds + KOFF + 2 * KBUF;
        #pragma unroll
        for (int nt = 0; nt < NT; ++nt) {
            int m = nt * 16 + lr;
            f16x8 bh = *(const f16x8*)(kb + ((m << 2) + (lk ^ ((lr >> 1) & 3))) * 16);
            acc[nt] = __builtin_amdgcn_mfma_f32_16x16x32_f16(ah, bh, acc[nt], 0, 0, 0);
            acc[nt] = __builtin_amdgcn_mfma_f32_16x16x32_f16(al, bh, acc[nt], 0, 0, 0);
        }
    }
    __syncthreads();                            // QK LDS dead; P/V may overlay

    stageV(0, 0); stageV(1, 1);                 // V latency hides under softmax

    // ---------- softmax, fully in-register (r11 verbatim; wave owns rows w*16..+15) ----------
    char* Pb = lds + w * 4096;
    {
        float rm[4] = {-3e38f, -3e38f, -3e38f, -3e38f};
        #pragma unroll
        for (int nt = 0; nt < NT; ++nt) {
            int m = nt * 16 + lr;
            #pragma unroll
            for (int r = 0; r < 4; ++r) {
                float s = (m < MM) ? (acc[nt][r] + dec[nt]) : -3e38f;
                acc[nt][r] = s;
                rm[r] = fmaxf(rm[r], s);
            }
        }
        #pragma unroll
        for (int r = 0; r < 4; ++r)
            #pragma unroll
            for (int off = 1; off < 16; off <<= 1)
                rm[r] = fmaxf(rm[r], __shfl_xor(rm[r], off));
        float rs[4] = {0.f, 0.f, 0.f, 0.f};
        #pragma unroll
        for (int nt = 0; nt < NT; ++nt)
            #pragma unroll
            for (int r = 0; r < 4; ++r) {
                float e = __expf(acc[nt][r] - rm[r]);
                acc[nt][r] = e;
                rs[r] += e;
            }
        #pragma unroll
        for (int r = 0; r < 4; ++r)
            #pragma unroll
            for (int off = 1; off < 16; off <<= 1)
                rs[r] += __shfl_xor(rs[r], off);
        #pragma unroll
        for (int r = 0; r < 4; ++r) {
            float inv = 1.f / rs[r];
            int row = 4 * lk + r;
            #pragma unroll
            for (int nt = 0; nt < NT; ++nt)
                *(_Float16*)(Pb + row * 256 + (((nt * 2 + (lr >> 3)) ^ row) & 15) * 16
                             + (lr & 7) * 2) = (_Float16)(acc[nt][r] * inv);
        }
    }
    if (lane < 32) {                            // zero-pad P cols 112..127 (slots 14,15)
        int row = lane >> 1, sl = 14 + (lane & 1);
        uint4 z = {0u, 0u, 0u, 0u};
        *(uint4*)(Pb + row * 256 + ((sl ^ row) & 15) * 16) = z;
    }
    WAITV(4);                                   // V(0) done; newer = V(1) x4
    __builtin_amdgcn_s_barrier();

    // ---------- PV: 16 steps of 64 cols (256 B/row/step), depth-3, counted vmcnt ----------
    f16x8 pa[4];
    #pragma unroll
    for (int k4 = 0; k4 < 4; ++k4)
        pa[k4] = *(const f16x8*)(Pb + lr * 256 + (((k4 * 4 + lk) ^ lr) & 15) * 16);

    for (int c = 0; c < 16; ++c) {
        if (c + 2 < 16) stageV((c + 2) % 3, c + 2);
        const char* vb = lds + VOFF + (c % 3) * VBUF;
        f32x4 o0 = {0.f,0.f,0.f,0.f}, o1 = {0.f,0.f,0.f,0.f};
        f32x4 o2 = {0.f,0.f,0.f,0.f}, o3 = {0.f,0.f,0.f,0.f};
        #pragma unroll
        for (int k4 = 0; k4 < 4; ++k4) {
            const char* vb2 = vb + (((k4 * 4 + lk) ^ lr) & 15) * 16;
            f16x8 b0 = *(const f16x8*)(vb2 + lr * 256);          // d-local = lr
            f16x8 b1 = *(const f16x8*)(vb2 + (16 + lr) * 256);
            f16x8 b2 = *(const f16x8*)(vb2 + (32 + lr) * 256);
            f16x8 b3 = *(const f16x8*)(vb2 + (48 + lr) * 256);   // (d&15)=lr for all
            o0 = __builtin_amdgcn_mfma_f32_16x16x32_f16(pa[k4], b0, o0, 0, 0, 0);
            o1 = __builtin_amdgcn_mfma_f32_16x16x32_f16(pa[k4], b1, o1, 0, 0, 0);
            o2 = __builtin_amdgcn_mfma_f32_16x16x32_f16(pa[k4], b2, o2, 0, 0, 0);
            o3 = __builtin_amdgcn_mfma_f32_16x16x32_f16(pa[k4], b3, o3, 0, 0, 0);
        }
        #pragma unroll
        for (int r = 0; r < 4; ++r) {
            size_t rw = (size_t)(row0 + w * 16 + 4 * lk + r) * DQ + c * 64;
            __builtin_nontemporal_store(o0[r], &out[rw + lr]);
            __builtin_nontemporal_store(o1[r], &out[rw + 16 + lr]);
            __builtin_nontemporal_store(o2[r], &out[rw + 32 + lr]);
            __builtin_nontemporal_store(o3[r], &out[rw + 48 + lr]);
        }
        // Ledger (stage 4 first, then 16 stores per step):
        //  c=0: V(1) from prologue -> newer = c0 ops 20 -> WAITV(20)
        //  1<=c<=13: V(c+1) staged at c-1 before stores -> newer = 16 + 20 = 36
        //  c=14: no stage at 14 -> newer = stores(13) 16 + stores(14) 16 = 32
        //  c=15: last step, no wait
        if (c == 0)       { WAITV(20); }
        else if (c <= 13) { WAITV(36); }
        else if (c == 14) { WAITV(32); }
        if (c < 15) __builtin_amdgcn_s_barrier();
    }
}

extern "C" void kernel_launch(void* const* d_in, const int* in_sizes, int n_in,
                              void* d_out, int out_size, void* d_ws, size_t ws_size,
                              hipStream_t stream) {
    const float* q  = (const float*)d_in[0];
    const float* cx = (const float*)d_in[1];
    const float* mk = (const float*)d_in[2];
    const float* mv = (const float*)d_in[3];
    const float* mc = (const float*)d_in[4];
    const float* ts = (const float*)d_in[5];
    float* out = (float*)d_out;

    _Float16* wsp = (_Float16*)d_ws;
    _Float16* KH = wsp;                        // [112][1056]
    _Float16* VT = wsp + KE;                   // [1024][128]

    const int B = in_sizes[0] / DQ;            // 131072

    build_k<<<dim3(17, 112), dim3(64), 0, stream>>>(mk, mc, KH);
    build_vt<<<dim3(512), dim3(256), 0, stream>>>(mv, VT);
    epmem_pipe<<<dim3(B / 64), dim3(256), 0, stream>>>(q, cx, ts, KH, VT, out);
}